// Round 9
// baseline (382.898 us; speedup 1.0000x reference)
//
#include <hip/hip_runtime.h>
#include <hip/hip_bf16.h>

// Causal attention, S=4096, d=1024, fp32 in/out.
// bf16 MFMA for projections and PV; fp8 e4m3 MFMA (BK=128B) for scores only.
// fp8 placement (round-6): V/P fp8 leak raw e4m3 error into O on weight-
// concentrated rows; Q/K fp8 error cancels under renormalization (measured
// +0.02 absmax). Precision budget is spent.
//
// Round-9: k_reduce fused into k_pv via split-K last-block-reduces (device-
// scope atomic counter + threadfence release/acquire). Early tiles' reductions
// overlap later tiles' MFMA; one launch gap removed. Counters zeroed by the
// cast kernel each call (ws is re-poisoned 0xAA before every launch).
//
// Workspace (256 MiB):
//   [0,8M)    x_bf  [4096,1024] bf16
//   [8M,12M)  Wqk   [2048,1024] bf16 (Wq rows 0..1023, Wk rows 1024..2047)
//   [12M,14M) Wv_bf [1024,1024] bf16
//   [14M,22M) QK    [4096,2048] fp8  (Q cols 0..1023, K cols 1024..2047)
//   [22M,30M) Vt    [1024,4096] bf16 (V^T, computed directly as Wv @ x^T)
//   [30M,62M) P~    [4096,4096] bf16 (exp(s/32), masked, unnormalized)
//   [62M,63M) rowsum_part [4096][64] fp32 (slot bn; dead slots zeroed)
//   [63M,+1K) counters [256] int (split-K completion counts)
//   [64M,112M) PV fp32 partials (96 multi-split groups x 8 bn x 64 KB)

typedef __bf16 bf16_t;
typedef __bf16 bf16x4v __attribute__((ext_vector_type(4)));
typedef __bf16 bf16x8 __attribute__((ext_vector_type(8)));
typedef float f32x4 __attribute__((ext_vector_type(4)));
typedef unsigned char u8;
typedef long long i64_t;

#define AS1 __attribute__((address_space(1)))
#define AS3 __attribute__((address_space(3)))

__device__ __forceinline__ void async_copy16(const void* g, void* l) {
    // 16B/lane direct global->LDS; LDS dest = wave-uniform base + lane*16
    __builtin_amdgcn_global_load_lds((AS1 void*)(g), (AS3 void*)(l), 16, 0, 0);
}

__device__ __forceinline__ u8 f32_to_fp8(float v) {
    // OCP e4m3 on gfx950 (HW conversion); layout validated in round 6
    return (u8)(__builtin_amdgcn_cvt_pk_fp8_f32(v, v, 0, false) & 0xff);
}

__device__ __forceinline__ void store_conv(float* p, float v) { *p = v; }
__device__ __forceinline__ void store_conv(bf16_t* p, float v) { *p = (bf16_t)v; }
__device__ __forceinline__ void store_conv(u8* p, float v) { *p = f32_to_fp8(v); }

// Sum of 64 consecutive floats (16x float4), for 1/rowsum computation.
__device__ __forceinline__ float sum64(const float* p) {
    const f32x4* v = (const f32x4*)p;
    float s = 0.f;
#pragma unroll
    for (int u = 0; u < 16; ++u) {
        f32x4 a = v[u];
        s += a[0] + a[1] + a[2] + a[3];
    }
    return s;
}

// ---------------- bf16 tile: BM=128, BN=128, BK=64 ------------------------
// XOR-swizzled LDS (16B chunk b of row r holds k-chunk b^(r&7)) -> conflict-
// free staging writes and ds_read_b128 fragment reads. kb in [kb0,kb1).
// EPI 0: C = v*alpha | EPI 2: C = v * inv[row] (inv indexed by tile-local row)
template <int EPI, typename OutT>
__device__ __forceinline__ void gemm_tile_bf16(const bf16_t* __restrict__ A, int lda,
                                               const bf16_t* __restrict__ B, int ldb,
                                               OutT* __restrict__ C, int ldc,
                                               int kb0, int kb1, float alpha,
                                               bf16_t* __restrict__ As,
                                               bf16_t* __restrict__ Bs,
                                               const float* __restrict__ inv) {
    constexpr int BK = 64;
    const int tid = threadIdx.x;
    const int lane = tid & 63, wave = tid >> 6;
    const int wm = wave >> 1, wn = wave & 1;
    const int q = lane >> 4, l16 = lane & 15;

    f32x4 acc[4][4] = {};

    const bf16_t* aSrc[4];
    const bf16_t* bSrc[4];
    int ldsOff[4];
#pragma unroll
    for (int it = 0; it < 4; ++it) {
        int c = it * 256 + tid;
        int r = c >> 3, b = c & 7;
        int sb = b ^ (r & 7);
        aSrc[it] = A + (size_t)r * lda + sb * 8;
        bSrc[it] = B + (size_t)r * ldb + sb * 8;
        ldsOff[it] = c * 8;
    }

    for (int kb = kb0; kb < kb1; ++kb) {
        const int k0 = kb * BK;
#pragma unroll
        for (int it = 0; it < 4; ++it) async_copy16(aSrc[it] + k0, &As[ldsOff[it]]);
#pragma unroll
        for (int it = 0; it < 4; ++it) async_copy16(bSrc[it] + k0, &Bs[ldsOff[it]]);
        __syncthreads();

#pragma unroll
        for (int k2 = 0; k2 < 2; ++k2) {
            bf16x8 af[4], bfr[4];
#pragma unroll
            for (int mt = 0; mt < 4; ++mt) {
                int m = wm * 64 + mt * 16 + l16;
                int blk = (k2 * 4 + q) ^ (m & 7);
                af[mt] = *(const bf16x8*)&As[m * BK + blk * 8];
            }
#pragma unroll
            for (int nt = 0; nt < 4; ++nt) {
                int nn = wn * 64 + nt * 16 + l16;
                int blk = (k2 * 4 + q) ^ (nn & 7);
                bfr[nt] = *(const bf16x8*)&Bs[nn * BK + blk * 8];
            }
#pragma unroll
            for (int mt = 0; mt < 4; ++mt)
#pragma unroll
                for (int nt = 0; nt < 4; ++nt)
                    acc[mt][nt] = __builtin_amdgcn_mfma_f32_16x16x32_bf16(
                        af[mt], bfr[nt], acc[mt][nt], 0, 0, 0);
        }
        __syncthreads();
    }

    // C/D layout: col = lane&15, row = (lane>>4)*4 + reg
    const int row0 = wm * 64, col0 = wn * 64;
#pragma unroll
    for (int mt = 0; mt < 4; ++mt)
#pragma unroll
        for (int nt = 0; nt < 4; ++nt)
#pragma unroll
            for (int r = 0; r < 4; ++r) {
                int lr = row0 + mt * 16 + q * 4 + r;
                float v = acc[mt][nt][r];
                v = (EPI == 2) ? v * inv[lr] : v * alpha;
                store_conv(&C[(size_t)lr * ldc + col0 + nt * 16 + l16], v);
            }
}

// ---------------- fp8 scores tile: BM=128, BN=64, BK=128 bytes ------------
// mfma_f32_16x16x32_fp8_fp8 (i64 frags, 8B/lane: m=lane&15, k=quad*8+j).
// LDS row = 128B = 8 16B chunks, chunk cb of row r at slot cb^(r&7).
// Epilogue: C = bf16(exp(v*alpha)) causally masked + per-row partial sums.
__device__ __forceinline__ void scores_tile_fp8(const u8* __restrict__ A, int lda,
                                                const u8* __restrict__ B, int ldb,
                                                bf16_t* __restrict__ C, int ldc,
                                                float alpha,
                                                u8* __restrict__ As, u8* __restrict__ Bs,
                                                float* __restrict__ partial,
                                                int gr0, int gc0,
                                                float* __restrict__ sred) {
    const int tid = threadIdx.x;
    const int lane = tid & 63, wave = tid >> 6;
    const int wm = wave >> 1, wn = wave & 1;
    const int q = lane >> 4, l16 = lane & 15;

    f32x4 acc[4][2] = {};

    const u8* aSrc[4];
    int aOff[4];
#pragma unroll
    for (int it = 0; it < 4; ++it) {
        int c = it * 256 + tid;
        int r = c >> 3, b = c & 7;
        int sb = b ^ (r & 7);
        aSrc[it] = A + (size_t)r * lda + sb * 16;
        aOff[it] = c * 16;
    }
    const u8* bSrc[2];
    int bOff[2];
#pragma unroll
    for (int it = 0; it < 2; ++it) {
        int c = it * 256 + tid;
        int r = c >> 3, b = c & 7;
        int sb = b ^ (r & 7);
        bSrc[it] = B + (size_t)r * ldb + sb * 16;
        bOff[it] = c * 16;
    }

    for (int kb = 0; kb < 8; ++kb) {
        const int k0 = kb * 128;
#pragma unroll
        for (int it = 0; it < 4; ++it) async_copy16(aSrc[it] + k0, &As[aOff[it]]);
#pragma unroll
        for (int it = 0; it < 2; ++it) async_copy16(bSrc[it] + k0, &Bs[bOff[it]]);
        __syncthreads();

#pragma unroll
        for (int k2 = 0; k2 < 4; ++k2) {
            i64_t af[4], bfr[2];
            const int cb = 2 * k2 + (q >> 1), co = (q & 1) * 8;
#pragma unroll
            for (int mt = 0; mt < 4; ++mt) {
                int m = wm * 64 + mt * 16 + l16;
                af[mt] = *(const i64_t*)&As[m * 128 + ((cb ^ (m & 7)) << 4) + co];
            }
#pragma unroll
            for (int nt = 0; nt < 2; ++nt) {
                int nn = wn * 32 + nt * 16 + l16;
                bfr[nt] = *(const i64_t*)&Bs[nn * 128 + ((cb ^ (nn & 7)) << 4) + co];
            }
#pragma unroll
            for (int mt = 0; mt < 4; ++mt)
#pragma unroll
                for (int nt = 0; nt < 2; ++nt)
                    acc[mt][nt] = __builtin_amdgcn_mfma_f32_16x16x32_fp8_fp8(
                        af[mt], bfr[nt], acc[mt][nt], 0, 0, 0);
        }
        __syncthreads();
    }

    // Epilogue: P = exp(v*alpha) masked, bf16; per-row sums via 16-lane shfl.
    const int row0 = wm * 64, col0 = wn * 32;
    float esum[4][4];
#pragma unroll
    for (int mt = 0; mt < 4; ++mt)
#pragma unroll
        for (int r = 0; r < 4; ++r) esum[mt][r] = 0.f;
#pragma unroll
    for (int mt = 0; mt < 4; ++mt)
#pragma unroll
        for (int nt = 0; nt < 2; ++nt)
#pragma unroll
            for (int r = 0; r < 4; ++r) {
                int lr = row0 + mt * 16 + q * 4 + r;
                int lc = col0 + nt * 16 + l16;
                float p = (gc0 + lc > gr0 + lr) ? 0.f : __expf(acc[mt][nt][r] * alpha);
                esum[mt][r] += p;
                C[(size_t)lr * ldc + lc] = (bf16_t)p;
            }
#pragma unroll
    for (int mt = 0; mt < 4; ++mt)
#pragma unroll
        for (int r = 0; r < 4; ++r) {
#pragma unroll
            for (int off = 1; off < 16; off <<= 1)
                esum[mt][r] += __shfl_xor(esum[mt][r], off, 64);
            if (l16 == 0) sred[(row0 + mt * 16 + q * 4 + r) * 2 + wn] = esum[mt][r];
        }
    __syncthreads();
    if (tid < 128) partial[(size_t)tid * 64] = sred[tid * 2] + sred[tid * 2 + 1];
}

// Fused projections, 768 blocks (3/CU), 16 bf16 kb-iters each:
//   b in [0,512):   QK = x @ [Wq;Wk]^T  [4096,2048] -> fp8
//   b in [512,768): Vt = Wv @ x^T       [1024,4096] -> bf16
__global__ __launch_bounds__(256) void k_qkv(const bf16_t* __restrict__ xb,
                                             const bf16_t* __restrict__ wqk,
                                             const bf16_t* __restrict__ wvb,
                                             u8* __restrict__ qk,
                                             bf16_t* __restrict__ vt) {
    __shared__ __attribute__((aligned(16))) bf16_t As[128 * 64];
    __shared__ __attribute__((aligned(16))) bf16_t Bs[128 * 64];
    int b = blockIdx.x;
    if (b < 512) {
        int bmi = b & 3, bn = (b >> 2) & 15, bmo = b >> 6;
        int bm = bmo * 4 + bmi;
        gemm_tile_bf16<0, u8>(xb + (size_t)bm * 128 * 1024, 1024,
                              wqk + (size_t)bn * 128 * 1024, 1024,
                              qk + (size_t)bm * 128 * 2048 + bn * 128, 2048,
                              0, 16, 1.f, As, Bs, nullptr);
    } else {
        int t = b - 512;
        int bm = t & 7, bn = t >> 3;  // bn 0..31
        gemm_tile_bf16<0, bf16_t>(wvb + (size_t)bm * 128 * 1024, 1024,
                                  xb + (size_t)bn * 128 * 1024, 1024,
                                  vt + (size_t)bm * 128 * 4096 + bn * 128, 4096,
                                  0, 16, 1.f, As, Bs, nullptr);
    }
}

// P~ = exp((Q @ K^T)/32) causal, 128x64 tiles, fp8 in / bf16 out, 8 kb-iters.
// Compact grid of all 1056 live tiles: t = bm^2+bm+bn. Emits per-row partial
// sums into rowsum_part[row][bn]; diagonal blocks (bn==2bm+1) also zero the
// unused slots [2bm+2,64) so consumers can sum all 64 unconditionally.
__global__ __launch_bounds__(256) void k_scores(const u8* __restrict__ qk,
                                                bf16_t* __restrict__ P,
                                                float* __restrict__ rowsum_part) {
    __shared__ __attribute__((aligned(16))) u8 As[128 * 128];
    __shared__ __attribute__((aligned(16))) u8 Bs[64 * 128];
    __shared__ float sred[128 * 2];
    int t = blockIdx.x;
    int bm = (int)((sqrtf(4.f * (float)t + 1.f) - 1.f) * 0.5f);
    while (bm * bm + bm > t) --bm;
    while ((bm + 1) * (bm + 1) + (bm + 1) <= t) ++bm;
    int bn = t - bm * bm - bm;  // 0 .. 2bm+1
    scores_tile_fp8(qk + (size_t)bm * 128 * 2048, 2048,
                    qk + 1024 + (size_t)bn * 64 * 2048, 2048,
                    P + (size_t)bm * 128 * 4096 + bn * 64, 4096,
                    0.03125f, As, Bs,
                    rowsum_part + (size_t)bm * 128 * 64 + bn,
                    bm * 128, bn * 64, sred);
    if (bn == 2 * bm + 1) {  // zero dead rowsum slots for this row block
        float* rp = rowsum_part + (size_t)bm * 128 * 64;
        int tid = threadIdx.x;
        for (int r = tid >> 4; r < 128; r += 16)
            for (int u = 2 * bm + 2 + (tid & 15); u < 64; u += 16)
                rp[r * 64 + u] = 0.f;
    }
}

// O = (P~ @ V) * diag(1/rowsum), bf16, BK=64: nk = 2(bm+1) iters, split-K
// chunk 12: 102 (bm,s) groups x 8 bn = 816 compact blocks (3.2/CU), <=12
// iters each. Single-split (bm<=5) stores direct with 1/rowsum scaling.
// Multi-split: write fp32 partial, release-fence, bump counter; the LAST
// block for the (bm,bn) tile acquires, sums all partials (u ascending, same
// order as the old k_reduce -> bit-identical), scales, stores. Reductions
// overlap other tiles' MFMA instead of running as a separate serial kernel.
__global__ __launch_bounds__(256) void k_pv(const bf16_t* __restrict__ P,
                                            const bf16_t* __restrict__ vt,
                                            const float* __restrict__ rowsum_part,
                                            float* __restrict__ out,
                                            float* __restrict__ partials,
                                            int* __restrict__ counters) {
    __shared__ __attribute__((aligned(16))) bf16_t As[128 * 64];
    __shared__ __attribute__((aligned(16))) bf16_t Bs[128 * 64];
    __shared__ float sInv[128];
    __shared__ int lastFlag;
    int b = blockIdx.x;
    int bn = b & 7, g = b >> 3;
    int bm, s, ns;
    if (g < 6)       { bm = g;                 s = 0;            ns = 1; }
    else if (g < 18) { bm = 6 + (g - 6) / 2;   s = (g - 6) % 2;  ns = 2; }
    else if (g < 36) { bm = 12 + (g - 18) / 3; s = (g - 18) % 3; ns = 3; }
    else if (g < 60) { bm = 18 + (g - 36) / 4; s = (g - 36) % 4; ns = 4; }
    else if (g < 90) { bm = 24 + (g - 60) / 5; s = (g - 60) % 5; ns = 5; }
    else             { bm = 30 + (g - 90) / 6; s = (g - 90) % 6; ns = 6; }
    int nk = 2 * (bm + 1);
    int kb0 = s * nk / ns;
    int kb1 = (s + 1) * nk / ns;
    int tid = threadIdx.x;

    const bf16_t* A = P + (size_t)bm * 128 * 4096;
    const bf16_t* B = vt + (size_t)bn * 128 * 4096;
    if (ns == 1) {
        if (tid < 128)
            sInv[tid] = 1.f / sum64(rowsum_part + (size_t)(bm * 128 + tid) * 64);
        // sInv visibility covered by the K-loop's __syncthreads (nk >= 2)
        gemm_tile_bf16<2, float>(A, 4096, B, 4096,
                                 out + (size_t)bm * 128 * 1024 + bn * 128, 1024,
                                 kb0, kb1, 1.f, As, Bs, sInv);
        return;
    }

    int cum = (bm < 12) ? (bm - 6) * 2
            : (bm < 18) ? 12 + (bm - 12) * 3
            : (bm < 24) ? 30 + (bm - 18) * 4
            : (bm < 30) ? 54 + (bm - 24) * 5
                        : 84 + (bm - 30) * 6;
    gemm_tile_bf16<0, float>(A, 4096, B, 4096,
                             partials + ((size_t)(cum + s) * 8 + bn) * 16384, 128,
                             kb0, kb1, 1.f, As, Bs, nullptr);

    // release our partial, count completions; last block reduces the tile
    __threadfence();
    if (tid == 0) {
        int old = __hip_atomic_fetch_add(&counters[bm * 8 + bn], 1,
                                         __ATOMIC_ACQ_REL, __HIP_MEMORY_SCOPE_AGENT);
        lastFlag = (old == ns - 1);
    }
    __syncthreads();
    if (!lastFlag) return;
    __threadfence();  // acquire: make all splits' partials visible

    if (tid < 128)
        sInv[tid] = 1.f / sum64(rowsum_part + (size_t)(bm * 128 + tid) * 64);
    __syncthreads();

    const float* base = partials + (size_t)cum * 8 * 16384 + (size_t)bn * 16384;
    for (int idx = tid * 4; idx < 16384; idx += 1024) {
        float sx = 0.f, sy = 0.f, sz = 0.f, sw = 0.f;
        for (int u = 0; u < ns; ++u) {
            const float4 v = *(const float4*)(base + (size_t)u * 8 * 16384 + idx);
            sx += v.x; sy += v.y; sz += v.z; sw += v.w;
        }
        int lr = idx >> 7, lc = idx & 127;
        float inv = sInv[lr];
        float4 o = {sx * inv, sy * inv, sz * inv, sw * inv};
        *(float4*)(out + (size_t)(bm * 128 + lr) * 1024 + bn * 128 + lc) = o;
    }
}

// fp32 -> bf16 casts: x -> x_bf, Wq|Wk -> Wqk (concat), Wv -> Wv_bf.
// Also zeroes the 256 split-K counters (ws is poisoned before every launch).
__global__ __launch_bounds__(256) void cast_to_bf16(const float* __restrict__ x,
                                                    const float* __restrict__ Wq,
                                                    const float* __restrict__ Wk,
                                                    const float* __restrict__ Wv,
                                                    bf16_t* __restrict__ xb,
                                                    bf16_t* __restrict__ wqk,
                                                    bf16_t* __restrict__ wv,
                                                    int* __restrict__ counters) {
    const int NX = (4096 * 1024) / 4;
    const int NW = (1024 * 1024) / 4;
    int idx = blockIdx.x * 256 + threadIdx.x;
    if (blockIdx.x == 0) counters[threadIdx.x] = 0;
    const float* src;
    bf16_t* dst;
    int off;
    if (idx < NX) {
        src = x; dst = xb; off = idx;
    } else if (idx < NX + NW) {
        src = Wq; dst = wqk; off = idx - NX;
    } else if (idx < NX + 2 * NW) {
        src = Wk; dst = wqk + (size_t)NW * 4; off = idx - NX - NW;
    } else {
        src = Wv; dst = wv; off = idx - NX - 2 * NW;
    }
    float4 f = ((const float4*)src)[off];
    bf16x4v o;
    o.x = (bf16_t)f.x; o.y = (bf16_t)f.y; o.z = (bf16_t)f.z; o.w = (bf16_t)f.w;
    *(bf16x4v*)(dst + (size_t)off * 4) = o;
}

extern "C" void kernel_launch(void* const* d_in, const int* in_sizes, int n_in,
                              void* d_out, int out_size, void* d_ws, size_t ws_size,
                              hipStream_t stream) {
    (void)in_sizes; (void)n_in; (void)out_size; (void)ws_size;
    const float* x  = (const float*)d_in[0];
    const float* Wq = (const float*)d_in[1];
    const float* Wk = (const float*)d_in[2];
    const float* Wv = (const float*)d_in[3];
    float* out = (float*)d_out;

    char* ws = (char*)d_ws;
    bf16_t* xb   = (bf16_t*)(ws + (size_t)0);
    bf16_t* wqk  = (bf16_t*)(ws + ((size_t)8 << 20));
    bf16_t* wvb  = (bf16_t*)(ws + ((size_t)12 << 20));
    u8*     qk   = (u8*)(ws + ((size_t)14 << 20));
    bf16_t* vt   = (bf16_t*)(ws + ((size_t)22 << 20));
    bf16_t* P    = (bf16_t*)(ws + ((size_t)30 << 20));
    float* rowsp = (float*)(ws + ((size_t)62 << 20));
    int*   cnts  = (int*)(ws + ((size_t)63 << 20));
    float* parts = (float*)(ws + ((size_t)64 << 20));

    cast_to_bf16<<<7168, 256, 0, stream>>>(x, Wq, Wk, Wv, xb, wqk, wvb, cnts);

    // QK (fp8) = x@[Wq;Wk]^T and Vt (bf16) = Wv@x^T (768 blocks, 3/CU)
    k_qkv<<<768, 256, 0, stream>>>(xb, wqk, wvb, qk, vt);

    // P~ = exp((Q@K^T)/32) causal + row partial sums (+dead-slot zeroing)
    k_scores<<<1056, 256, 0, stream>>>(qk, P, rowsp);

    // out = (P~ @ V) * diag(1/rowsum): split-K with fused last-block reduce
    k_pv<<<816, 256, 0, stream>>>(P, vt, rowsp, out, parts, cnts);
}

// Round 10
// 189.210 us; speedup vs baseline: 2.0237x; 2.0237x over previous
//
#include <hip/hip_runtime.h>
#include <hip/hip_bf16.h>

// Causal attention, S=4096, d=1024, fp32 in/out.
// bf16 MFMA for projections and PV; fp8 e4m3 MFMA (BK=128B) for scores only.
// fp8 placement (round-6): V/P fp8 leak raw e4m3 error into O; Q/K fp8 error
// cancels under renormalization (measured +0.02 absmax). Budget spent.
//
// Round-10: REVERT round-9's fused last-block-reduce (device-scope
// __threadfence on gfx950 = per-XCD L2 writeback/invalidate -> 768 L2 flushes
// nuked all locality: FETCH 50->104MB, 10x slower). Cross-block dataflow
// stays at kernel boundaries. On top of round-8:
//  - k_scores at 128x128 tiles (528 live, 8 fp8 iters) -> half the iter-slots
//  - Vt-projection blocks merged into the k_scores launch (784 blocks,
//    Vt first: per-CU ~1 Vt + 2 score blocks, balanced); k_qkv = QK only
//
// Workspace (256 MiB):
//   [0,8M)    x_bf  [4096,1024] bf16
//   [8M,12M)  Wqk   [2048,1024] bf16 (Wq rows 0..1023, Wk rows 1024..2047)
//   [12M,14M) Wv_bf [1024,1024] bf16
//   [14M,22M) QK    [4096,2048] fp8  (Q cols 0..1023, K cols 1024..2047)
//   [22M,30M) Vt    [1024,4096] bf16 (V^T, computed directly as Wv @ x^T)
//   [30M,62M) P~    [4096,4096] bf16 (exp(s/32), masked, unnormalized)
//   [62M,62.5M) rowsum_part [4096][32] fp32 (slot bn; dead slots zeroed)
//   [64M,100M) PV fp32 partials (72 multi-split groups x 8 bn x 64 KB)

typedef __bf16 bf16_t;
typedef __bf16 bf16x4v __attribute__((ext_vector_type(4)));
typedef __bf16 bf16x8 __attribute__((ext_vector_type(8)));
typedef float f32x4 __attribute__((ext_vector_type(4)));
typedef unsigned char u8;
typedef long long i64_t;

#define AS1 __attribute__((address_space(1)))
#define AS3 __attribute__((address_space(3)))

__device__ __forceinline__ void async_copy16(const void* g, void* l) {
    // 16B/lane direct global->LDS; LDS dest = wave-uniform base + lane*16
    __builtin_amdgcn_global_load_lds((AS1 void*)(g), (AS3 void*)(l), 16, 0, 0);
}

__device__ __forceinline__ u8 f32_to_fp8(float v) {
    // OCP e4m3 on gfx950 (HW conversion); layout validated in round 6
    return (u8)(__builtin_amdgcn_cvt_pk_fp8_f32(v, v, 0, false) & 0xff);
}

__device__ __forceinline__ void store_conv(float* p, float v) { *p = v; }
__device__ __forceinline__ void store_conv(bf16_t* p, float v) { *p = (bf16_t)v; }
__device__ __forceinline__ void store_conv(u8* p, float v) { *p = f32_to_fp8(v); }

// Sum of 32 consecutive floats (8x float4), for 1/rowsum computation.
__device__ __forceinline__ float sum32(const float* p) {
    const f32x4* v = (const f32x4*)p;
    float s = 0.f;
#pragma unroll
    for (int u = 0; u < 8; ++u) {
        f32x4 a = v[u];
        s += a[0] + a[1] + a[2] + a[3];
    }
    return s;
}

// ---------------- bf16 tile: BM=128, BN=128, BK=64 ------------------------
// XOR-swizzled LDS (16B chunk b of row r holds k-chunk b^(r&7)) -> conflict-
// free staging writes and ds_read_b128 fragment reads. kb in [kb0,kb1).
// EPI 0: C = v*alpha | EPI 2: C = v * inv[row] (inv indexed by tile-local row)
template <int EPI, typename OutT>
__device__ __forceinline__ void gemm_tile_bf16(const bf16_t* __restrict__ A, int lda,
                                               const bf16_t* __restrict__ B, int ldb,
                                               OutT* __restrict__ C, int ldc,
                                               int kb0, int kb1, float alpha,
                                               bf16_t* __restrict__ As,
                                               bf16_t* __restrict__ Bs,
                                               const float* __restrict__ inv) {
    constexpr int BK = 64;
    const int tid = threadIdx.x;
    const int lane = tid & 63, wave = tid >> 6;
    const int wm = wave >> 1, wn = wave & 1;
    const int q = lane >> 4, l16 = lane & 15;

    f32x4 acc[4][4] = {};

    const bf16_t* aSrc[4];
    const bf16_t* bSrc[4];
    int ldsOff[4];
#pragma unroll
    for (int it = 0; it < 4; ++it) {
        int c = it * 256 + tid;
        int r = c >> 3, b = c & 7;
        int sb = b ^ (r & 7);
        aSrc[it] = A + (size_t)r * lda + sb * 8;
        bSrc[it] = B + (size_t)r * ldb + sb * 8;
        ldsOff[it] = c * 8;
    }

    for (int kb = kb0; kb < kb1; ++kb) {
        const int k0 = kb * BK;
#pragma unroll
        for (int it = 0; it < 4; ++it) async_copy16(aSrc[it] + k0, &As[ldsOff[it]]);
#pragma unroll
        for (int it = 0; it < 4; ++it) async_copy16(bSrc[it] + k0, &Bs[ldsOff[it]]);
        __syncthreads();

#pragma unroll
        for (int k2 = 0; k2 < 2; ++k2) {
            bf16x8 af[4], bfr[4];
#pragma unroll
            for (int mt = 0; mt < 4; ++mt) {
                int m = wm * 64 + mt * 16 + l16;
                int blk = (k2 * 4 + q) ^ (m & 7);
                af[mt] = *(const bf16x8*)&As[m * BK + blk * 8];
            }
#pragma unroll
            for (int nt = 0; nt < 4; ++nt) {
                int nn = wn * 64 + nt * 16 + l16;
                int blk = (k2 * 4 + q) ^ (nn & 7);
                bfr[nt] = *(const bf16x8*)&Bs[nn * BK + blk * 8];
            }
#pragma unroll
            for (int mt = 0; mt < 4; ++mt)
#pragma unroll
                for (int nt = 0; nt < 4; ++nt)
                    acc[mt][nt] = __builtin_amdgcn_mfma_f32_16x16x32_bf16(
                        af[mt], bfr[nt], acc[mt][nt], 0, 0, 0);
        }
        __syncthreads();
    }

    // C/D layout: col = lane&15, row = (lane>>4)*4 + reg
    const int row0 = wm * 64, col0 = wn * 64;
#pragma unroll
    for (int mt = 0; mt < 4; ++mt)
#pragma unroll
        for (int nt = 0; nt < 4; ++nt)
#pragma unroll
            for (int r = 0; r < 4; ++r) {
                int lr = row0 + mt * 16 + q * 4 + r;
                float v = acc[mt][nt][r];
                v = (EPI == 2) ? v * inv[lr] : v * alpha;
                store_conv(&C[(size_t)lr * ldc + col0 + nt * 16 + l16], v);
            }
}

// ---------------- fp8 scores tile: 128x128, BK=128 bytes ------------------
// mfma_f32_16x16x32_fp8_fp8 (i64 frags, 8B/lane: m=lane&15, k=quad*8+j).
// LDS row = 128B = 8 16B chunks, chunk cb of row r at slot cb^(r&7).
// Epilogue: C = bf16(exp(v*alpha)) causally masked + per-row partial sums
// into `partial` (pre-offset, stride 32 floats).
__device__ __forceinline__ void scores_tile_fp8(const u8* __restrict__ A, int lda,
                                                const u8* __restrict__ B, int ldb,
                                                bf16_t* __restrict__ C, int ldc,
                                                float alpha,
                                                u8* __restrict__ As, u8* __restrict__ Bs,
                                                float* __restrict__ partial,
                                                int gr0, int gc0,
                                                float* __restrict__ sred) {
    const int tid = threadIdx.x;
    const int lane = tid & 63, wave = tid >> 6;
    const int wm = wave >> 1, wn = wave & 1;
    const int q = lane >> 4, l16 = lane & 15;

    f32x4 acc[4][4] = {};

    const u8* aSrc[4];
    const u8* bSrc[4];
    int ldsOff[4];
#pragma unroll
    for (int it = 0; it < 4; ++it) {
        int c = it * 256 + tid;
        int r = c >> 3, b = c & 7;
        int sb = b ^ (r & 7);
        aSrc[it] = A + (size_t)r * lda + sb * 16;
        bSrc[it] = B + (size_t)r * ldb + sb * 16;
        ldsOff[it] = c * 16;
    }

    for (int kb = 0; kb < 8; ++kb) {
        const int k0 = kb * 128;
#pragma unroll
        for (int it = 0; it < 4; ++it) async_copy16(aSrc[it] + k0, &As[ldsOff[it]]);
#pragma unroll
        for (int it = 0; it < 4; ++it) async_copy16(bSrc[it] + k0, &Bs[ldsOff[it]]);
        __syncthreads();

#pragma unroll
        for (int k2 = 0; k2 < 4; ++k2) {
            i64_t af[4], bfr[4];
            const int cb = 2 * k2 + (q >> 1), co = (q & 1) * 8;
#pragma unroll
            for (int mt = 0; mt < 4; ++mt) {
                int m = wm * 64 + mt * 16 + l16;
                af[mt] = *(const i64_t*)&As[m * 128 + ((cb ^ (m & 7)) << 4) + co];
            }
#pragma unroll
            for (int nt = 0; nt < 4; ++nt) {
                int nn = wn * 64 + nt * 16 + l16;
                bfr[nt] = *(const i64_t*)&Bs[nn * 128 + ((cb ^ (nn & 7)) << 4) + co];
            }
#pragma unroll
            for (int mt = 0; mt < 4; ++mt)
#pragma unroll
                for (int nt = 0; nt < 4; ++nt)
                    acc[mt][nt] = __builtin_amdgcn_mfma_f32_16x16x32_fp8_fp8(
                        af[mt], bfr[nt], acc[mt][nt], 0, 0, 0);
        }
        __syncthreads();
    }

    // Epilogue: P = exp(v*alpha) masked, bf16; per-row sums via 16-lane shfl.
    const int row0 = wm * 64, col0 = wn * 64;
    float esum[4][4];
#pragma unroll
    for (int mt = 0; mt < 4; ++mt)
#pragma unroll
        for (int r = 0; r < 4; ++r) esum[mt][r] = 0.f;
#pragma unroll
    for (int mt = 0; mt < 4; ++mt)
#pragma unroll
        for (int nt = 0; nt < 4; ++nt)
#pragma unroll
            for (int r = 0; r < 4; ++r) {
                int lr = row0 + mt * 16 + q * 4 + r;
                int lc = col0 + nt * 16 + l16;
                float p = (gc0 + lc > gr0 + lr) ? 0.f : __expf(acc[mt][nt][r] * alpha);
                esum[mt][r] += p;
                C[(size_t)lr * ldc + lc] = (bf16_t)p;
            }
#pragma unroll
    for (int mt = 0; mt < 4; ++mt)
#pragma unroll
        for (int r = 0; r < 4; ++r) {
#pragma unroll
            for (int off = 1; off < 16; off <<= 1)
                esum[mt][r] += __shfl_xor(esum[mt][r], off, 64);
            if (l16 == 0) sred[(row0 + mt * 16 + q * 4 + r) * 2 + wn] = esum[mt][r];
        }
    __syncthreads();
    if (tid < 128) partial[(size_t)tid * 32] = sred[tid * 2] + sred[tid * 2 + 1];
}

// QK projection only: 512 uniform blocks (2/CU), 16 bf16 kb-iters each.
// QK = x @ [Wq;Wk]^T -> [4096,2048] fp8.
__global__ __launch_bounds__(256) void k_qkv(const bf16_t* __restrict__ xb,
                                             const bf16_t* __restrict__ wqk,
                                             u8* __restrict__ qk) {
    __shared__ __attribute__((aligned(16))) bf16_t As[128 * 64];
    __shared__ __attribute__((aligned(16))) bf16_t Bs[128 * 64];
    int b = blockIdx.x;
    int bm = b & 31, bn = b >> 5;  // bn 0..15
    gemm_tile_bf16<0, u8>(xb + (size_t)bm * 128 * 1024, 1024,
                          wqk + (size_t)bn * 128 * 1024, 1024,
                          qk + (size_t)bm * 128 * 2048 + bn * 128, 2048,
                          0, 16, 1.f, As, Bs, nullptr);
}

// Merged dispatch, 784 blocks (~3/CU):
//   b in [0,256):   Vt = Wv @ x^T [1024,4096] bf16 (16 bf16 iters)
//   b in [256,784): P~ = exp((Q@K^T)/32) causal 128x128 tiles, fp8, 8 iters;
//     compact tri grid t = bm(bm+1)/2 + bn (528 tiles); emits per-row partial
//     sums; diagonal tiles (bn==bm) zero dead slots [bm+1,32).
// Vt-first ordering: each CU gets ~1 long Vt block + ~2 short score blocks.
__global__ __launch_bounds__(256) void k_sv(const bf16_t* __restrict__ xb,
                                            const bf16_t* __restrict__ wvb,
                                            const u8* __restrict__ qk,
                                            bf16_t* __restrict__ vt,
                                            bf16_t* __restrict__ P,
                                            float* __restrict__ rowsum_part) {
    __shared__ __attribute__((aligned(16))) char smem[33 * 1024 + 1024];
    int b = blockIdx.x;
    if (b < 256) {
        bf16_t* As = (bf16_t*)smem;
        bf16_t* Bs = (bf16_t*)(smem + 16384);
        int bm = b & 7, bn = b >> 3;  // bn 0..31
        gemm_tile_bf16<0, bf16_t>(wvb + (size_t)bm * 128 * 1024, 1024,
                                  xb + (size_t)bn * 128 * 1024, 1024,
                                  vt + (size_t)bm * 128 * 4096 + bn * 128, 4096,
                                  0, 16, 1.f, As, Bs, nullptr);
        return;
    }
    u8* As = (u8*)smem;
    u8* Bs = (u8*)(smem + 16384);
    float* sred = (float*)(smem + 32768);
    int t = b - 256;  // 0..527
    int bm = (int)((sqrtf(8.f * (float)t + 1.f) - 1.f) * 0.5f);
    while (bm * (bm + 1) / 2 > t) --bm;
    while ((bm + 1) * (bm + 2) / 2 <= t) ++bm;
    int bn = t - bm * (bm + 1) / 2;  // 0..bm
    scores_tile_fp8(qk + (size_t)bm * 128 * 2048, 2048,
                    qk + 1024 + (size_t)bn * 128 * 2048, 2048,
                    P + (size_t)bm * 128 * 4096 + bn * 128, 4096,
                    0.03125f, As, Bs,
                    rowsum_part + (size_t)bm * 128 * 32 + bn,
                    bm * 128, bn * 128, sred);
    if (bn == bm) {  // zero dead rowsum slots for this row block
        float* rp = rowsum_part + (size_t)bm * 128 * 32;
        int tid = threadIdx.x;
        for (int r = tid >> 4; r < 128; r += 16)
            for (int u = bm + 1 + (tid & 15); u < 32; u += 16)
                rp[r * 32 + u] = 0.f;
    }
}

// O = (P~ @ V) * diag(1/rowsum), bf16, BK=64: nk = 2(bm+1) iters.
// Split-K chunk 16: 80 (bm,s) groups x 8 bn = 640 compact blocks (2.5/CU).
// Single-split (bm<=7) computes 1/rowsum into LDS and stores direct;
// multi-split writes fp32 partials for k_reduce.
__global__ __launch_bounds__(256) void k_pv(const bf16_t* __restrict__ P,
                                            const bf16_t* __restrict__ vt,
                                            const float* __restrict__ rowsum_part,
                                            float* __restrict__ out,
                                            float* __restrict__ partials) {
    __shared__ __attribute__((aligned(16))) bf16_t As[128 * 64];
    __shared__ __attribute__((aligned(16))) bf16_t Bs[128 * 64];
    __shared__ float sInv[128];
    int b = blockIdx.x;
    int bn = b & 7, g = b >> 3;
    int bm, s, ns;
    if (g < 8)       { bm = g;                 s = 0;            ns = 1; }
    else if (g < 24) { bm = 8 + (g - 8) / 2;   s = (g - 8) % 2;  ns = 2; }
    else if (g < 48) { bm = 16 + (g - 24) / 3; s = (g - 24) % 3; ns = 3; }
    else             { bm = 24 + (g - 48) / 4; s = (g - 48) % 4; ns = 4; }
    int nk = 2 * (bm + 1);
    int kb0 = s * nk / ns;
    int kb1 = (s + 1) * nk / ns;

    const bf16_t* A = P + (size_t)bm * 128 * 4096;
    const bf16_t* B = vt + (size_t)bn * 128 * 4096;
    if (ns == 1) {
        int tid = threadIdx.x;
        if (tid < 128)
            sInv[tid] = 1.f / sum32(rowsum_part + (size_t)(bm * 128 + tid) * 32);
        // visibility of sInv covered by the K-loop's __syncthreads (nk >= 2)
        gemm_tile_bf16<2, float>(A, 4096, B, 4096,
                                 out + (size_t)bm * 128 * 1024 + bn * 128, 1024,
                                 kb0, kb1, 1.f, As, Bs, sInv);
    } else {
        int cum = (bm < 16) ? (bm - 8) * 2
                : (bm < 24) ? 16 + (bm - 16) * 3
                            : 40 + (bm - 24) * 4;
        gemm_tile_bf16<0, float>(A, 4096, B, 4096,
                                 partials + ((size_t)(cum + s) * 8 + bn) * 16384, 128,
                                 kb0, kb1, 1.f, As, Bs, nullptr);
    }
}

// out tiles for bm in [8,31]: sum 2..4 fp32 partials, scale by 1/rowsum.
// Compact 3072 blocks: t = b%192 -> (bm-8, bn); p = b/192 -> tile 16th
// (8 rows x 128 cols per block); float4/thread.
__global__ __launch_bounds__(256) void k_reduce(const float* __restrict__ partials,
                                                const float* __restrict__ rowsum_part,
                                                float* __restrict__ out) {
    int b = blockIdx.x;
    int t = b % 192, p = b / 192;
    int bm = t % 24 + 8, bn = t / 24;
    int ns = (bm < 16) ? 2 : (bm < 24) ? 3 : 4;
    int cum = (bm < 16) ? (bm - 8) * 2
            : (bm < 24) ? 16 + (bm - 16) * 3
                        : 40 + (bm - 24) * 4;
    __shared__ float sInv[8];
    int tid = threadIdx.x;
    if (tid < 8) {
        int row = bm * 128 + p * 8 + tid;
        sInv[tid] = 1.f / sum32(rowsum_part + (size_t)row * 32);
    }
    __syncthreads();

    int idx = p * 1024 + tid * 4;
    int lr = idx >> 7, lc = idx & 127;
    float sx = 0.f, sy = 0.f, sz = 0.f, sw = 0.f;
    for (int u = 0; u < ns; ++u) {
        const float4 v = *(const float4*)(partials + ((size_t)(cum + u) * 8 + bn) * 16384 + idx);
        sx += v.x; sy += v.y; sz += v.z; sw += v.w;
    }
    float inv = sInv[lr - p * 8];
    float4 o = {sx * inv, sy * inv, sz * inv, sw * inv};
    *(float4*)(out + (size_t)(bm * 128 + lr) * 1024 + bn * 128 + lc) = o;
}

// fp32 -> bf16 casts: x -> x_bf, Wq|Wk -> Wqk (concat), Wv -> Wv_bf.
__global__ __launch_bounds__(256) void cast_to_bf16(const float* __restrict__ x,
                                                    const float* __restrict__ Wq,
                                                    const float* __restrict__ Wk,
                                                    const float* __restrict__ Wv,
                                                    bf16_t* __restrict__ xb,
                                                    bf16_t* __restrict__ wqk,
                                                    bf16_t* __restrict__ wv) {
    const int NX = (4096 * 1024) / 4;
    const int NW = (1024 * 1024) / 4;
    int idx = blockIdx.x * 256 + threadIdx.x;
    const float* src;
    bf16_t* dst;
    int off;
    if (idx < NX) {
        src = x; dst = xb; off = idx;
    } else if (idx < NX + NW) {
        src = Wq; dst = wqk; off = idx - NX;
    } else if (idx < NX + 2 * NW) {
        src = Wk; dst = wqk + (size_t)NW * 4; off = idx - NX - NW;
    } else {
        src = Wv; dst = wv; off = idx - NX - 2 * NW;
    }
    float4 f = ((const float4*)src)[off];
    bf16x4v o;
    o.x = (bf16_t)f.x; o.y = (bf16_t)f.y; o.z = (bf16_t)f.z; o.w = (bf16_t)f.w;
    *(bf16x4v*)(dst + (size_t)off * 4) = o;
}

extern "C" void kernel_launch(void* const* d_in, const int* in_sizes, int n_in,
                              void* d_out, int out_size, void* d_ws, size_t ws_size,
                              hipStream_t stream) {
    (void)in_sizes; (void)n_in; (void)out_size; (void)ws_size;
    const float* x  = (const float*)d_in[0];
    const float* Wq = (const float*)d_in[1];
    const float* Wk = (const float*)d_in[2];
    const float* Wv = (const float*)d_in[3];
    float* out = (float*)d_out;

    char* ws = (char*)d_ws;
    bf16_t* xb   = (bf16_t*)(ws + (size_t)0);
    bf16_t* wqk  = (bf16_t*)(ws + ((size_t)8 << 20));
    bf16_t* wvb  = (bf16_t*)(ws + ((size_t)12 << 20));
    u8*     qk   = (u8*)(ws + ((size_t)14 << 20));
    bf16_t* vt   = (bf16_t*)(ws + ((size_t)22 << 20));
    bf16_t* P    = (bf16_t*)(ws + ((size_t)30 << 20));
    float* rowsp = (float*)(ws + ((size_t)62 << 20));
    float* parts = (float*)(ws + ((size_t)64 << 20));

    cast_to_bf16<<<7168, 256, 0, stream>>>(x, Wq, Wk, Wv, xb, wqk, wvb);

    // QK (fp8) = x@[Wq;Wk]^T (512 blocks, 2/CU)
    k_qkv<<<512, 256, 0, stream>>>(xb, wqk, qk);

    // Vt (bf16) = Wv@x^T + P~ = exp((Q@K^T)/32) causal 128x128 (784 blocks)
    k_sv<<<784, 256, 0, stream>>>(xb, wvb, qk, vt, P, rowsp);

    // out = (P~ @ V) * diag(1/rowsum): split-K chunk 16 + partial reduction
    k_pv<<<640, 256, 0, stream>>>(P, vt, rowsp, out, parts);
    k_reduce<<<3072, 256, 0, stream>>>(parts, rowsp, out);
}